// Round 5
// baseline (244.061 us; speedup 1.0000x reference)
//
#include <hip/hip_runtime.h>

#define NB   32
#define H    1024
#define W    1024
#define BAND 8               // output rows per block
#define NBANDS (H / BAND)    // 128 bands per image
#define TOPK 200
#define NMS_THRESH 0.1f
#define HI_THRESH  0.999f    // fast-path split; exact fallback preserved
#define CAPH 32              // hi keys per band bucket (E~8)
#define LBL  384             // lo bucket capacity cap (E~167, ~+16 sigma)

typedef unsigned long long ull;

__device__ __forceinline__ float4 fmax4(float4 a, float4 b) {
    return make_float4(fmaxf(a.x, b.x), fmaxf(a.y, b.y),
                       fmaxf(a.z, b.z), fmaxf(a.w, b.w));
}

// ---------------- Phase 1: 7x7 NMS, request-minimized ----------------
// R4 counter evidence: duration invariant to cache warmth (82us at both
// 114MB and 11MB FETCH) -> bound by vector-memory REQUEST throughput
// (~1 lane-request/cy/CU = 16B/lane/cy): 42 lane-requests/thread = 72us
// floor. Fix: load ONLY the own quad (14 requests/thread, 3x fewer);
// neighbor quads come from LDS (stage 7-row half = 28KB, ds_write_b128 +
// 2x ds_read_b128/row; stride-1 -> 2-way bank aliasing = free, m136).
// Clamp semantics move into LDS indices (t==0 reads own quad: duplicated
// edge cols are already window members -> exact, as verified originally).
// Robust to load sinking: 12 waves/CU x 64 lanes x few wave-loads >> the
// ~900 outstanding requests needed to stay throughput-bound.
__global__ __launch_bounds__(256, 3) void peak_kernel(
    const float* __restrict__ in,
    ull* __restrict__ cand_hi,   // [NB*NBANDS][CAPH]
    ull* __restrict__ cand_lo,   // [NB*NBANDS][capl]
    int* __restrict__ cntl,      // [NB*NBANDS], raw atomic counts (may exceed capl)
    int* __restrict__ cnth,      // [NB*NBANDS], raw atomic counts (may exceed CAPH)
    int capl)
{
    __shared__ float rowbuf[7][1024];   // 28 KB: one 7-row half

    const int img  = blockIdx.y;
    const int band = blockIdx.x;
    const int R0   = band * BAND;
    const char* base = (const char*)(in + ((size_t)img << 20));
    const int t = threadIdx.x;

    const int cb = t << 4;                         // own quad byte offset
    const int fL = (t == 0)   ? 0    : (t << 2) - 4;   // clamped left quad (floats)
    const int fR = (t == 255) ? 1020 : (t << 2) + 4;   // clamped right quad

    const int bkt = img * NBANDS + band;
    ull* glo = cand_lo + (size_t)bkt * capl;
    ull* ghi = cand_hi + (size_t)bkt * CAPH;

    float4 acc[BAND];  // running vertical 7-max per output row
    float4 c[BAND];    // own centers for output rows (input rows 3..10)

    #pragma unroll
    for (int half = 0; half < 2; half++) {
        const int rb = half * 7;
        float4 oq[7];
        // ---- burst: 7 own-quad loads, no consumers ----
        #pragma unroll
        for (int r = 0; r < 7; r++) {
            const int ri = min(max(R0 - 3 + rb + r, 0), H - 1);  // exact clamp
            oq[r] = *(const float4*)(base + ((size_t)ri << 12) + cb);
        }
        if (half) __syncthreads();   // prev half fully consumed before overwrite
        #pragma unroll
        for (int r = 0; r < 7; r++)
            *(float4*)&rowbuf[r][t << 2] = oq[r];
        __syncthreads();
        // ---- consume: horizontal 7-max (neighbors from LDS), fold into acc ----
        #pragma unroll
        for (int r = 0; r < 7; r++) {
            float4 lq = *(const float4*)&rowbuf[r][fL];
            float4 rq = *(const float4*)&rowbuf[r][fR];
            float S3 = oq[r].x;
            float S2 = fmaxf(lq.w, S3);
            float S1 = fmaxf(lq.z, S2);
            float S0 = fmaxf(lq.y, S1);
            float P5 = fmaxf(oq[r].y, oq[r].z);
            float P6 = fmaxf(P5, oq[r].w);
            float P7 = fmaxf(P6, rq.x);
            float P8 = fmaxf(P7, rq.y);
            float P9 = fmaxf(P8, rq.z);
            float4 hr = make_float4(fmaxf(S0, P6), fmaxf(S1, P7),
                                    fmaxf(S2, P8), fmaxf(S3, P9));
            const int rr = rb + r;
            // h-row rr covers output rows ro in [rr-6, rr] ∩ [0, BAND)
            #pragma unroll
            for (int ro = 0; ro < BAND; ro++) {
                if (ro <= rr && ro >= rr - 6) {       // compile-time prune
                    if (ro == rr) acc[ro] = hr;       // first touch
                    else         acc[ro] = fmax4(acc[ro], hr);
                }
            }
            if (rr >= 3 && rr < 3 + BAND) c[rr - 3] = oq[r];
        }
    }

    // ---- emit: peak test + direct global append (R4-verified) ----
    #pragma unroll
    for (int ro = 0; ro < BAND; ro++) {
        float4 wm  = acc[ro];
        float4 ctr = c[ro];
        const int rg = R0 + ro;
        bool p0 = (ctr.x > NMS_THRESH) && (ctr.x == wm.x);
        bool p1 = (ctr.y > NMS_THRESH) && (ctr.y == wm.y);
        bool p2 = (ctr.z > NMS_THRESH) && (ctr.z == wm.z);
        bool p3 = (ctr.w > NMS_THRESH) && (ctr.w == wm.w);
        int cnt = (int)p0 + (int)p1 + (int)p2 + (int)p3;
        if (cnt) {                                // rare per thread-row (~8%)
            int s = atomicAdd(&cntl[bkt], cnt);
            unsigned ib = ((unsigned)rg << 10) | ((unsigned)t << 2);
            float cv[4] = {ctr.x, ctr.y, ctr.z, ctr.w};
            bool  pp[4] = {p0, p1, p2, p3};
            #pragma unroll
            for (int j = 0; j < 4; j++) {
                if (pp[j]) {
                    ull key = ((ull)__float_as_uint(cv[j]) << 32) |
                              (ull)(0xFFFFFFFFu - (ib + j));
                    if (s < capl) glo[s] = key;
                    s++;
                    if (cv[j] > HI_THRESH) {      // ~1/20 of peaks
                        int q = atomicAdd(&cnth[bkt], 1);
                        if (q < CAPH) ghi[q] = key;
                    }
                }
            }
        }
    }
}

// ---------------- Phase 2: per-image exact top-200 ----------------
// Byte-identical to the R4-verified kernel (raw atomic count semantics).
__global__ __launch_bounds__(256) void topk_kernel(
    const ull* __restrict__ cand_hi,
    const ull* __restrict__ cand_lo,
    const int* __restrict__ cntl,
    const int* __restrict__ cnth,
    float* __restrict__ out,
    int capl)
{
    const int img = blockIdx.x;
    const int t = threadIdx.x;
    const int wv = t >> 6;
    const int lane = t & 63;
    __shared__ ull stage[NBANDS * CAPH];   // 32 KB: all hi keys fit
    __shared__ unsigned hist[4][256];      // wave-private histograms
    __shared__ unsigned sfx[256];
    __shared__ ull sel[256];
    __shared__ int s_ch[NBANDS], s_cl[NBANDS], s_oh[NBANDS + 1];
    __shared__ int s_ok;
    __shared__ int scnt;
    __shared__ unsigned s_pref;
    __shared__ int s_k, s_stop;
    __shared__ unsigned aW[4], oW[4], s_and, s_or, wsum[4];

    if (t == 0) { s_ok = 1; s_stop = 0; scnt = 0; }
    __syncthreads();
    if (t < NBANDS) {
        int rawh = cnth[img * NBANDS + t];
        s_ch[t] = min(rawh, CAPH);
        s_cl[t] = min(cntl[img * NBANDS + t], capl);
        if (rawh > CAPH) s_ok = 0;   // hi keys dropped -> exact lo path
    }
    __syncthreads();
    if (t == 0) {
        int a = 0;
        for (int b = 0; b < NBANDS; b++) { s_oh[b] = a; a += s_ch[b]; }
        s_oh[NBANDS] = a;
    }
    __syncthreads();
    const int nh = s_oh[NBANDS];
    const bool use_hi = (nh >= TOPK) && (s_ok != 0);

    if (use_hi) {
        int b = t >> 1, i0 = t & 1;              // 2 threads per band
        int nb = s_ch[b], ob = s_oh[b];
        const ull* p = cand_hi + (size_t)(img * NBANDS + b) * CAPH;
        for (int i = i0; i < nb; i += 2) stage[ob + i] = p[i];
    }
    __syncthreads();

    int n_tot = nh;
    if (!use_hi) {
        n_tot = 0;
        for (int b = 0; b < NBANDS; b++) n_tot += s_cl[b];
    }

    unsigned T = 0;   // value-bits threshold (partial or exact)
    if (n_tot > 256) {
        // ---- AND/OR over candidate value bits -> common high-byte prefix
        unsigned va = 0xFFFFFFFFu, vo = 0u;
        if (use_hi) {
            for (int i = t; i < nh; i += 256) {
                unsigned vb = (unsigned)(stage[i] >> 32);
                va &= vb; vo |= vb;
            }
        } else {
            for (int b = 0; b < NBANDS; b++) {
                int nb = s_cl[b];
                const ull* p = cand_lo + (size_t)(img * NBANDS + b) * capl;
                for (int i = t; i < nb; i += 256) {
                    unsigned vb = (unsigned)(p[i] >> 32);
                    va &= vb; vo |= vb;
                }
            }
        }
        #pragma unroll
        for (int off = 32; off > 0; off >>= 1) {
            va &= __shfl_xor(va, off);
            vo |= __shfl_xor(vo, off);
        }
        if (lane == 0) { aW[wv] = va; oW[wv] = vo; }
        __syncthreads();
        if (t == 0) {
            unsigned A = 0xFFFFFFFFu, O = 0u;
            for (int w = 0; w < 4; w++) { A &= aW[w]; O |= oW[w]; }
            s_and = A; s_or = O;
        }
        __syncthreads();
        const unsigned diff = s_and ^ s_or;
        int sb = 3;
        unsigned maskhi = 0u;
        while (sb >= 0 && ((diff >> (sb * 8)) & 0xFFu) == 0u) {
            maskhi |= 0xFFu << (sb * 8);
            sb--;
        }
        unsigned prefix = s_and & maskhi;

        if (sb < 0) {
            T = s_and;               // all candidate values identical
        } else {
            int kk = TOPK;
            for (int byte = sb; byte >= 0; byte--) {
                #pragma unroll
                for (int w = 0; w < 4; w++) hist[w][t] = 0;
                __syncthreads();
                const int shift = byte * 8;
                if (use_hi) {
                    for (int i = t; i < nh; i += 256) {
                        unsigned vb = (unsigned)(stage[i] >> 32);
                        if ((vb & maskhi) == prefix)
                            atomicAdd(&hist[wv][(vb >> shift) & 0xFFu], 1u);
                    }
                } else {
                    for (int b = 0; b < NBANDS; b++) {
                        int nb = s_cl[b];
                        const ull* p = cand_lo + (size_t)(img * NBANDS + b) * capl;
                        for (int i = t; i < nb; i += 256) {
                            unsigned vb = (unsigned)(p[i] >> 32);
                            if ((vb & maskhi) == prefix)
                                atomicAdd(&hist[wv][(vb >> shift) & 0xFFu], 1u);
                        }
                    }
                }
                __syncthreads();
                // suffix-scan of 256 bins: wave shuffle (2 barriers)
                unsigned v = hist[0][t] + hist[1][t] + hist[2][t] + hist[3][t];
                #pragma unroll
                for (int off = 1; off < 64; off <<= 1) {
                    unsigned u = __shfl_down(v, off);
                    if (lane + off < 64) v += u;
                }
                if (lane == 0) wsum[wv] = v;
                __syncthreads();
                unsigned add = 0;
                for (int w = wv + 1; w < 4; w++) add += wsum[w];
                unsigned myfx = v + add;         // count(matching, byte >= t)
                sfx[t] = myfx;
                __syncthreads();
                unsigned nxt = (t == 255) ? 0u : sfx[t + 1];
                if (myfx >= (unsigned)kk && nxt < (unsigned)kk) {
                    s_pref = prefix | ((unsigned)t << shift);
                    s_k = kk - (int)nxt;
                    // candidates {vb >= new partial T} = (TOPK-kk) + myfx
                    if ((TOPK - kk) + (int)myfx <= 256) s_stop = 1;
                }
                __syncthreads();
                prefix = s_pref;
                kk = s_k;
                maskhi |= (0xFFu << shift);
                if (s_stop) break;
            }
            T = prefix;
        }
    }

    __syncthreads();
    if (use_hi) {
        for (int i = t; i < nh; i += 256) {
            ull k = stage[i];
            if ((unsigned)(k >> 32) >= T) {
                int s = atomicAdd(&scnt, 1);
                if (s < 256) sel[s] = k;
            }
        }
    } else {
        for (int b = 0; b < NBANDS; b++) {
            int nb = s_cl[b];
            const ull* p = cand_lo + (size_t)(img * NBANDS + b) * capl;
            for (int i = t; i < nb; i += 256) {
                ull k = p[i];
                if ((unsigned)(k >> 32) >= T) {
                    int s = atomicAdd(&scnt, 1);
                    if (s < 256) sel[s] = k;
                }
            }
        }
    }
    __syncthreads();
    const int m = min(scnt, 256);
    ull* sorted = stage;               // stage is dead past this point
    if (t >= m) sel[t] = 0ull;
    sorted[t] = 0ull;
    __syncthreads();

    // ---- rank-select: exact descending order of unique full keys ----
    {
        ull k = sel[t];
        int rank = 0;
        for (int j = 0; j < 256; j++) rank += (sel[j] > k) ? 1 : 0;
        if (k != 0ull && rank < 256) sorted[rank] = k;
    }
    __syncthreads();

    // write: coords [NB,TOPK,2] then probs [NB,TOPK], all fp32
    if (t < TOPK) {
        ull key = sorted[t];
        float prob = 0.0f;
        unsigned row = 0, col = 0;
        if (key != 0ull) {
            prob = __uint_as_float((unsigned)(key >> 32));
            unsigned idx = 0xFFFFFFFFu - (unsigned)(key & 0xFFFFFFFFull);
            row = idx >> 10;
            col = idx & (W - 1);
        }
        size_t cbase = (size_t)img * TOPK * 2 + (size_t)t * 2;
        out[cbase + 0] = (float)row;
        out[cbase + 1] = (float)col;
        out[(size_t)NB * TOPK * 2 + (size_t)img * TOPK + t] = prob;
    }
}

extern "C" void kernel_launch(void* const* d_in, const int* in_sizes, int n_in,
                              void* d_out, int out_size, void* d_ws, size_t ws_size,
                              hipStream_t stream) {
    const float* center_map = (const float*)d_in[0];
    float* out = (float*)d_out;

    // workspace layout:
    //   [0, 16K)      : cntl[4096]   (zeroed: peak emits via atomics)
    //   [16K, 32K)    : cnth[4096]   (zeroed)
    //   [32K, +1M)    : cand_hi[4096][CAPH]
    //   rest          : cand_lo[4096][capl]
    const int nbkt = NB * NBANDS;   // 4096
    int* cntl = (int*)d_ws;
    int* cnth = (int*)((char*)d_ws + 16384);
    ull* cand_hi = (ull*)((char*)d_ws + 32768);
    size_t hi_bytes = (size_t)nbkt * CAPH * sizeof(ull);   // 1 MB
    ull* cand_lo = (ull*)((char*)d_ws + 32768 + hi_bytes);
    size_t avail = (ws_size > 32768 + hi_bytes) ? (ws_size - 32768 - hi_bytes) : 0;
    int capl = (int)(avail / (nbkt * sizeof(ull)));
    if (capl > LBL) capl = LBL;
    if (capl < 1) capl = 1;

    hipMemsetAsync(d_ws, 0, 32768, stream);   // 32 KB counters, capture-safe

    dim3 gridA(NBANDS, NB);   // 128 x 32 = 4096 blocks
    peak_kernel<<<gridA, 256, 0, stream>>>(center_map, cand_hi, cand_lo,
                                           cntl, cnth, capl);

    topk_kernel<<<NB, 256, 0, stream>>>(cand_hi, cand_lo, cntl, cnth, out, capl);
}

// Round 6
// 228.350 us; speedup vs baseline: 1.0688x; 1.0688x over previous
//
#include <hip/hip_runtime.h>

#define NB   32
#define H    1024
#define W    1024
#define BAND 8               // output rows per block
#define NBANDS (H / BAND)    // 128 bands per image
#define NROWS 14             // input rows per block (BAND + 6 halo)
#define TOPK 200
#define NMS_THRESH 0.1f
#define HI_THRESH  0.999f    // fast-path split; exact fallback preserved
#define CAPH 32              // hi keys per band bucket (E~8)
#define LBL  384             // lo bucket capacity cap (E~167, ~+16 sigma)

typedef unsigned long long ull;

__device__ __forceinline__ float4 fmax4(float4 a, float4 b) {
    return make_float4(fmaxf(a.x, b.x), fmaxf(a.y, b.y),
                       fmaxf(a.z, b.z), fmaxf(a.w, b.w));
}

// ---------------- Phase 1: 7x7 NMS, vertical-first separable ----------------
// R4/R5 lesson (counter-proven): __launch_bounds__ min-blocks=3 caps VGPR at
// ~170 and FORCES the compiler to sink the burst loads (VGPR 64/68, serial
// latency chains, warmth-invariant 82-97us). (256,2) = 256-VGPR budget is
// what keeps the burst alive (R3: 77us). This kernel:
//   - 14 own-quad global loads in ONE burst (no consumers) -> ~56 VGPR live;
//     14 lane-requests/thread vs 42 in the R3 kernel (own+left+right).
//   - vertical 7-max folded in REGISTERS (own columns only, no cross-thread
//     data): acc[8], raw-row clamp duplicates are window members -> exact.
//   - only the 8 vmax rows staged in LDS (32KB) for the horizontal pass:
//     24 LDS ops/thread (R5 had 42), ONE barrier (R5 had 3).
//   - direct-atomic emit (R4-verified), no emit buffers/barriers.
__global__ __launch_bounds__(256, 2) void peak_kernel(
    const float* __restrict__ in,
    ull* __restrict__ cand_hi,   // [NB*NBANDS][CAPH]
    ull* __restrict__ cand_lo,   // [NB*NBANDS][capl]
    int* __restrict__ cntl,      // [NB*NBANDS], raw atomic counts (may exceed capl)
    int* __restrict__ cnth,      // [NB*NBANDS], raw atomic counts (may exceed CAPH)
    int capl)
{
    __shared__ float vbuf[BAND][1024];   // 32 KB: vertical-max rows

    const int img  = blockIdx.y;
    const int band = blockIdx.x;
    const int R0   = band * BAND;
    const char* base = (const char*)(in + ((size_t)img << 20));
    const int t = threadIdx.x;

    const int cb = t << 4;                             // own quad byte offset
    const int fL = (t == 0)   ? 0    : (t << 2) - 4;   // clamped left quad (floats)
    const int fR = (t == 255) ? 1020 : (t << 2) + 4;   // clamped right quad

    const int bkt = img * NBANDS + band;
    ull* glo = cand_lo + (size_t)bkt * capl;
    ull* ghi = cand_hi + (size_t)bkt * CAPH;

    // ---- burst: 14 independent own-quad loads, zero consumers ----
    float4 oq[NROWS];
    #pragma unroll
    for (int r = 0; r < NROWS; r++) {
        const int ri = min(max(R0 - 3 + r, 0), H - 1);   // exact row clamp
        oq[r] = *(const float4*)(base + ((size_t)ri << 12) + cb);
    }

    // ---- vertical 7-max in registers: acc[ro] = max(oq[ro..ro+6]) ----
    float4 acc[BAND];
    #pragma unroll
    for (int ro = 0; ro < BAND; ro++) {
        float4 a = fmax4(fmax4(fmax4(oq[ro], oq[ro + 1]),
                               fmax4(oq[ro + 2], oq[ro + 3])),
                         fmax4(fmax4(oq[ro + 4], oq[ro + 5]), oq[ro + 6]));
        acc[ro] = a;
        *(float4*)&vbuf[ro][t << 2] = a;
    }
    // centers: input row rg = R0+ro is oq[ro+3] (RA aliases, no copy cost)
    __syncthreads();   // all vmax rows visible before neighbor reads

    // ---- horizontal 7-max over vmax + peak emit ----
    #pragma unroll
    for (int ro = 0; ro < BAND; ro++) {
        float4 a  = acc[ro];
        float4 lq = *(const float4*)&vbuf[ro][fL];
        float4 rq = *(const float4*)&vbuf[ro][fR];
        float S3 = a.x;
        float S2 = fmaxf(lq.w, S3);
        float S1 = fmaxf(lq.z, S2);
        float S0 = fmaxf(lq.y, S1);
        float P5 = fmaxf(a.y, a.z);
        float P6 = fmaxf(P5, a.w);
        float P7 = fmaxf(P6, rq.x);
        float P8 = fmaxf(P7, rq.y);
        float P9 = fmaxf(P8, rq.z);
        float4 wm = make_float4(fmaxf(S0, P6), fmaxf(S1, P7),
                                fmaxf(S2, P8), fmaxf(S3, P9));
        float4 ctr = oq[ro + 3];
        const int rg = R0 + ro;
        bool p0 = (ctr.x > NMS_THRESH) && (ctr.x == wm.x);
        bool p1 = (ctr.y > NMS_THRESH) && (ctr.y == wm.y);
        bool p2 = (ctr.z > NMS_THRESH) && (ctr.z == wm.z);
        bool p3 = (ctr.w > NMS_THRESH) && (ctr.w == wm.w);
        int cnt = (int)p0 + (int)p1 + (int)p2 + (int)p3;
        if (cnt) {                                // rare per thread-row (~8%)
            int s = atomicAdd(&cntl[bkt], cnt);
            unsigned ib = ((unsigned)rg << 10) | ((unsigned)t << 2);
            float cv[4] = {ctr.x, ctr.y, ctr.z, ctr.w};
            bool  pp[4] = {p0, p1, p2, p3};
            #pragma unroll
            for (int j = 0; j < 4; j++) {
                if (pp[j]) {
                    ull key = ((ull)__float_as_uint(cv[j]) << 32) |
                              (ull)(0xFFFFFFFFu - (ib + j));
                    if (s < capl) glo[s] = key;
                    s++;
                    if (cv[j] > HI_THRESH) {      // ~1/20 of peaks
                        int q = atomicAdd(&cnth[bkt], 1);
                        if (q < CAPH) ghi[q] = key;
                    }
                }
            }
        }
    }
}

// ---------------- Phase 2: per-image exact top-200 ----------------
// Byte-identical to the R4/R5-verified kernel (raw atomic count semantics).
__global__ __launch_bounds__(256) void topk_kernel(
    const ull* __restrict__ cand_hi,
    const ull* __restrict__ cand_lo,
    const int* __restrict__ cntl,
    const int* __restrict__ cnth,
    float* __restrict__ out,
    int capl)
{
    const int img = blockIdx.x;
    const int t = threadIdx.x;
    const int wv = t >> 6;
    const int lane = t & 63;
    __shared__ ull stage[NBANDS * CAPH];   // 32 KB: all hi keys fit
    __shared__ unsigned hist[4][256];      // wave-private histograms
    __shared__ unsigned sfx[256];
    __shared__ ull sel[256];
    __shared__ int s_ch[NBANDS], s_cl[NBANDS], s_oh[NBANDS + 1];
    __shared__ int s_ok;
    __shared__ int scnt;
    __shared__ unsigned s_pref;
    __shared__ int s_k, s_stop;
    __shared__ unsigned aW[4], oW[4], s_and, s_or, wsum[4];

    if (t == 0) { s_ok = 1; s_stop = 0; scnt = 0; }
    __syncthreads();
    if (t < NBANDS) {
        int rawh = cnth[img * NBANDS + t];
        s_ch[t] = min(rawh, CAPH);
        s_cl[t] = min(cntl[img * NBANDS + t], capl);
        if (rawh > CAPH) s_ok = 0;   // hi keys dropped -> exact lo path
    }
    __syncthreads();
    if (t == 0) {
        int a = 0;
        for (int b = 0; b < NBANDS; b++) { s_oh[b] = a; a += s_ch[b]; }
        s_oh[NBANDS] = a;
    }
    __syncthreads();
    const int nh = s_oh[NBANDS];
    const bool use_hi = (nh >= TOPK) && (s_ok != 0);

    if (use_hi) {
        int b = t >> 1, i0 = t & 1;              // 2 threads per band
        int nb = s_ch[b], ob = s_oh[b];
        const ull* p = cand_hi + (size_t)(img * NBANDS + b) * CAPH;
        for (int i = i0; i < nb; i += 2) stage[ob + i] = p[i];
    }
    __syncthreads();

    int n_tot = nh;
    if (!use_hi) {
        n_tot = 0;
        for (int b = 0; b < NBANDS; b++) n_tot += s_cl[b];
    }

    unsigned T = 0;   // value-bits threshold (partial or exact)
    if (n_tot > 256) {
        // ---- AND/OR over candidate value bits -> common high-byte prefix
        unsigned va = 0xFFFFFFFFu, vo = 0u;
        if (use_hi) {
            for (int i = t; i < nh; i += 256) {
                unsigned vb = (unsigned)(stage[i] >> 32);
                va &= vb; vo |= vb;
            }
        } else {
            for (int b = 0; b < NBANDS; b++) {
                int nb = s_cl[b];
                const ull* p = cand_lo + (size_t)(img * NBANDS + b) * capl;
                for (int i = t; i < nb; i += 256) {
                    unsigned vb = (unsigned)(p[i] >> 32);
                    va &= vb; vo |= vb;
                }
            }
        }
        #pragma unroll
        for (int off = 32; off > 0; off >>= 1) {
            va &= __shfl_xor(va, off);
            vo |= __shfl_xor(vo, off);
        }
        if (lane == 0) { aW[wv] = va; oW[wv] = vo; }
        __syncthreads();
        if (t == 0) {
            unsigned A = 0xFFFFFFFFu, O = 0u;
            for (int w = 0; w < 4; w++) { A &= aW[w]; O |= oW[w]; }
            s_and = A; s_or = O;
        }
        __syncthreads();
        const unsigned diff = s_and ^ s_or;
        int sb = 3;
        unsigned maskhi = 0u;
        while (sb >= 0 && ((diff >> (sb * 8)) & 0xFFu) == 0u) {
            maskhi |= 0xFFu << (sb * 8);
            sb--;
        }
        unsigned prefix = s_and & maskhi;

        if (sb < 0) {
            T = s_and;               // all candidate values identical
        } else {
            int kk = TOPK;
            for (int byte = sb; byte >= 0; byte--) {
                #pragma unroll
                for (int w = 0; w < 4; w++) hist[w][t] = 0;
                __syncthreads();
                const int shift = byte * 8;
                if (use_hi) {
                    for (int i = t; i < nh; i += 256) {
                        unsigned vb = (unsigned)(stage[i] >> 32);
                        if ((vb & maskhi) == prefix)
                            atomicAdd(&hist[wv][(vb >> shift) & 0xFFu], 1u);
                    }
                } else {
                    for (int b = 0; b < NBANDS; b++) {
                        int nb = s_cl[b];
                        const ull* p = cand_lo + (size_t)(img * NBANDS + b) * capl;
                        for (int i = t; i < nb; i += 256) {
                            unsigned vb = (unsigned)(p[i] >> 32);
                            if ((vb & maskhi) == prefix)
                                atomicAdd(&hist[wv][(vb >> shift) & 0xFFu], 1u);
                        }
                    }
                }
                __syncthreads();
                // suffix-scan of 256 bins: wave shuffle (2 barriers)
                unsigned v = hist[0][t] + hist[1][t] + hist[2][t] + hist[3][t];
                #pragma unroll
                for (int off = 1; off < 64; off <<= 1) {
                    unsigned u = __shfl_down(v, off);
                    if (lane + off < 64) v += u;
                }
                if (lane == 0) wsum[wv] = v;
                __syncthreads();
                unsigned add = 0;
                for (int w = wv + 1; w < 4; w++) add += wsum[w];
                unsigned myfx = v + add;         // count(matching, byte >= t)
                sfx[t] = myfx;
                __syncthreads();
                unsigned nxt = (t == 255) ? 0u : sfx[t + 1];
                if (myfx >= (unsigned)kk && nxt < (unsigned)kk) {
                    s_pref = prefix | ((unsigned)t << shift);
                    s_k = kk - (int)nxt;
                    // candidates {vb >= new partial T} = (TOPK-kk) + myfx
                    if ((TOPK - kk) + (int)myfx <= 256) s_stop = 1;
                }
                __syncthreads();
                prefix = s_pref;
                kk = s_k;
                maskhi |= (0xFFu << shift);
                if (s_stop) break;
            }
            T = prefix;
        }
    }

    __syncthreads();
    if (use_hi) {
        for (int i = t; i < nh; i += 256) {
            ull k = stage[i];
            if ((unsigned)(k >> 32) >= T) {
                int s = atomicAdd(&scnt, 1);
                if (s < 256) sel[s] = k;
            }
        }
    } else {
        for (int b = 0; b < NBANDS; b++) {
            int nb = s_cl[b];
            const ull* p = cand_lo + (size_t)(img * NBANDS + b) * capl;
            for (int i = t; i < nb; i += 256) {
                ull k = p[i];
                if ((unsigned)(k >> 32) >= T) {
                    int s = atomicAdd(&scnt, 1);
                    if (s < 256) sel[s] = k;
                }
            }
        }
    }
    __syncthreads();
    const int m = min(scnt, 256);
    ull* sorted = stage;               // stage is dead past this point
    if (t >= m) sel[t] = 0ull;
    sorted[t] = 0ull;
    __syncthreads();

    // ---- rank-select: exact descending order of unique full keys ----
    {
        ull k = sel[t];
        int rank = 0;
        for (int j = 0; j < 256; j++) rank += (sel[j] > k) ? 1 : 0;
        if (k != 0ull && rank < 256) sorted[rank] = k;
    }
    __syncthreads();

    // write: coords [NB,TOPK,2] then probs [NB,TOPK], all fp32
    if (t < TOPK) {
        ull key = sorted[t];
        float prob = 0.0f;
        unsigned row = 0, col = 0;
        if (key != 0ull) {
            prob = __uint_as_float((unsigned)(key >> 32));
            unsigned idx = 0xFFFFFFFFu - (unsigned)(key & 0xFFFFFFFFull);
            row = idx >> 10;
            col = idx & (W - 1);
        }
        size_t cbase = (size_t)img * TOPK * 2 + (size_t)t * 2;
        out[cbase + 0] = (float)row;
        out[cbase + 1] = (float)col;
        out[(size_t)NB * TOPK * 2 + (size_t)img * TOPK + t] = prob;
    }
}

extern "C" void kernel_launch(void* const* d_in, const int* in_sizes, int n_in,
                              void* d_out, int out_size, void* d_ws, size_t ws_size,
                              hipStream_t stream) {
    const float* center_map = (const float*)d_in[0];
    float* out = (float*)d_out;

    // workspace layout:
    //   [0, 16K)      : cntl[4096]   (zeroed: peak emits via atomics)
    //   [16K, 32K)    : cnth[4096]   (zeroed)
    //   [32K, +1M)    : cand_hi[4096][CAPH]
    //   rest          : cand_lo[4096][capl]
    const int nbkt = NB * NBANDS;   // 4096
    int* cntl = (int*)d_ws;
    int* cnth = (int*)((char*)d_ws + 16384);
    ull* cand_hi = (ull*)((char*)d_ws + 32768);
    size_t hi_bytes = (size_t)nbkt * CAPH * sizeof(ull);   // 1 MB
    ull* cand_lo = (ull*)((char*)d_ws + 32768 + hi_bytes);
    size_t avail = (ws_size > 32768 + hi_bytes) ? (ws_size - 32768 - hi_bytes) : 0;
    int capl = (int)(avail / (nbkt * sizeof(ull)));
    if (capl > LBL) capl = LBL;
    if (capl < 1) capl = 1;

    hipMemsetAsync(d_ws, 0, 32768, stream);   // 32 KB counters, capture-safe

    dim3 gridA(NBANDS, NB);   // 128 x 32 = 4096 blocks
    peak_kernel<<<gridA, 256, 0, stream>>>(center_map, cand_hi, cand_lo,
                                           cntl, cnth, capl);

    topk_kernel<<<NB, 256, 0, stream>>>(cand_hi, cand_lo, cntl, cnth, out, capl);
}

// Round 7
// 203.830 us; speedup vs baseline: 1.1974x; 1.1203x over previous
//
#include <hip/hip_runtime.h>

#define NB   32
#define H    1024
#define W    1024
#define BAND 8               // output rows per block
#define NBANDS (H / BAND)    // 128 bands per image
#define NROWS 14             // input rows per block (BAND + 6 halo)
#define TOPK 200
#define NMS_THRESH 0.1f
#define HI_THRESH  0.999f    // fast-path split; exact fallback preserved
#define CAPH 32              // hi keys per band bucket (E~8)
#define LBL  384             // LDS lo buffer per block (E~167, ~+16 sigma)

typedef unsigned long long ull;

__device__ __forceinline__ float4 fmax4(float4 a, float4 b) {
    return make_float4(fmaxf(a.x, b.x), fmaxf(a.y, b.y),
                       fmaxf(a.z, b.z), fmaxf(a.w, b.w));
}
__device__ __forceinline__ float4 shfl_up4(float4 v) {
    return make_float4(__shfl_up(v.x, 1), __shfl_up(v.y, 1),
                       __shfl_up(v.z, 1), __shfl_up(v.w, 1));
}
__device__ __forceinline__ float4 shfl_dn4(float4 v) {
    return make_float4(__shfl_down(v.x, 1), __shfl_down(v.y, 1),
                       __shfl_down(v.z, 1), __shfl_down(v.w, 1));
}

// ---------------- Phase 1: 7x7 NMS, shuffle-horizontal ----------------
// R3-R6 evidence: all structures land 77-97us, warmth-invariant, no pipe
// >25% busy, occupancy 37% -> LATENCY-bound at ~3 blocks/CU (32KB LDS cap
// + convoys). Compiler sinks load bursts regardless of launch_bounds
// (falsified R6: VGPR 52 under a 256-VGPR budget). Lever = occupancy:
//   - 14 own-quad loads (request-minimal), vertical 7-max in registers.
//   - horizontal neighbors via wave shuffle of the vmax rows (lane+-1 =
//     left/right quad); only wave-boundary lanes use a 1KB LDS edge
//     buffer. LDS 32KB -> ~4.6KB, LDS ops 24 -> ~4/thread (masked).
//   - R3-verified LDS-staged emit + plain count stores: no global-atomic
//     counters -> NO hipMemsetAsync dispatch (R3 vs R4/R6 totals: ~10us).
__global__ __launch_bounds__(256) void peak_kernel(
    const float* __restrict__ in,
    ull* __restrict__ cand_hi,   // [NB*NBANDS][CAPH]
    ull* __restrict__ cand_lo,   // [NB*NBANDS][capl]
    int* __restrict__ cntl,      // [NB*NBANDS], clamped counts
    int* __restrict__ cnth,      // [NB*NBANDS], -1 => hi overflow -> lo path
    int capl)
{
    __shared__ float4 edge[BAND][4][2];  // 1 KB: per-wave boundary quads
    __shared__ ull lb_lo[LBL];           // 3 KB
    __shared__ ull lb_hi[CAPH];          // 256 B
    __shared__ int lc_lo, lc_hi;

    const int img  = blockIdx.y;
    const int band = blockIdx.x;
    const int R0   = band * BAND;
    const char* base = (const char*)(in + ((size_t)img << 20));
    const int t = threadIdx.x;
    const int lane = t & 63;
    const int wv   = t >> 6;

    if (t == 0) { lc_lo = 0; lc_hi = 0; }

    const int cb = t << 4;   // own quad byte offset

    // ---- burst: 14 independent own-quad loads ----
    float4 oq[NROWS];
    #pragma unroll
    for (int r = 0; r < NROWS; r++) {
        const int ri = min(max(R0 - 3 + r, 0), H - 1);   // exact row clamp
        oq[r] = *(const float4*)(base + ((size_t)ri << 12) + cb);
    }

    // ---- vertical 7-max in registers; stash wave-boundary quads ----
    float4 acc[BAND];
    #pragma unroll
    for (int ro = 0; ro < BAND; ro++) {
        float4 a = fmax4(fmax4(fmax4(oq[ro], oq[ro + 1]),
                               fmax4(oq[ro + 2], oq[ro + 3])),
                         fmax4(fmax4(oq[ro + 4], oq[ro + 5]), oq[ro + 6]));
        acc[ro] = a;
        if (lane == 0)  edge[ro][wv][0] = a;
        if (lane == 63) edge[ro][wv][1] = a;
    }
    __syncthreads();   // edge quads + lc init visible

    // ---- horizontal 7-max via shuffles + peak emit ----
    #pragma unroll
    for (int ro = 0; ro < BAND; ro++) {
        float4 a  = acc[ro];
        float4 lq = shfl_up4(a);      // lane-1's quad = cols 4t-4..4t-1
        float4 rq = shfl_dn4(a);      // lane+1's quad = cols 4t+4..4t+7
        if (lane == 0) {              // cross-wave / global-left clamp
            lq = a;
            if (t != 0) lq = edge[ro][wv - 1][1];
        }
        if (lane == 63) {             // cross-wave / global-right clamp
            rq = a;
            if (t != 255) rq = edge[ro][wv + 1][0];
        }
        float S3 = a.x;
        float S2 = fmaxf(lq.w, S3);
        float S1 = fmaxf(lq.z, S2);
        float S0 = fmaxf(lq.y, S1);
        float P5 = fmaxf(a.y, a.z);
        float P6 = fmaxf(P5, a.w);
        float P7 = fmaxf(P6, rq.x);
        float P8 = fmaxf(P7, rq.y);
        float P9 = fmaxf(P8, rq.z);
        float4 wm = make_float4(fmaxf(S0, P6), fmaxf(S1, P7),
                                fmaxf(S2, P8), fmaxf(S3, P9));
        float4 ctr = oq[ro + 3];
        const int rg = R0 + ro;
        bool p0 = (ctr.x > NMS_THRESH) && (ctr.x == wm.x);
        bool p1 = (ctr.y > NMS_THRESH) && (ctr.y == wm.y);
        bool p2 = (ctr.z > NMS_THRESH) && (ctr.z == wm.z);
        bool p3 = (ctr.w > NMS_THRESH) && (ctr.w == wm.w);
        int cnt = (int)p0 + (int)p1 + (int)p2 + (int)p3;
        if (cnt) {                                // rare per thread-row (~8%)
            int s = atomicAdd(&lc_lo, cnt);       // LDS-scope atomic
            unsigned ib = ((unsigned)rg << 10) | ((unsigned)t << 2);
            float cv[4] = {ctr.x, ctr.y, ctr.z, ctr.w};
            bool  pp[4] = {p0, p1, p2, p3};
            #pragma unroll
            for (int j = 0; j < 4; j++) {
                if (pp[j]) {
                    ull key = ((ull)__float_as_uint(cv[j]) << 32) |
                              (ull)(0xFFFFFFFFu - (ib + j));
                    if (s < LBL) lb_lo[s] = key;
                    s++;
                    if (cv[j] > HI_THRESH) {      // ~1/20 of peaks
                        int q = atomicAdd(&lc_hi, 1);
                        if (q < CAPH) lb_hi[q] = key;
                    }
                }
            }
        }
    }

    // ---- flush: coalesced stores to this block's private bucket ----
    __syncthreads();
    const int bkt = img * NBANDS + band;
    const int nl_raw = lc_lo, nh_raw = lc_hi;
    const int nl = min(nl_raw, min(LBL, capl));
    const int nh = min(nh_raw, CAPH);
    ull* glo = cand_lo + (size_t)bkt * capl;
    for (int i = t; i < nl; i += 256) glo[i] = lb_lo[i];
    ull* ghi = cand_hi + (size_t)bkt * CAPH;
    if (t < nh) ghi[t] = lb_hi[t];
    if (t == 0) {
        cntl[bkt] = nl;
        cnth[bkt] = (nh_raw > CAPH) ? -1 : nh_raw;   // -1: force exact lo path
    }
}

// ---------------- Phase 2: per-image exact top-200 ----------------
// Byte-identical to the R3-verified kernel (~17us): AND/OR prefix skip,
// early-exit radix, shuffle suffix-scan, rank-select.
__global__ __launch_bounds__(256) void topk_kernel(
    const ull* __restrict__ cand_hi,
    const ull* __restrict__ cand_lo,
    const int* __restrict__ cntl,
    const int* __restrict__ cnth,
    float* __restrict__ out,
    int capl)
{
    const int img = blockIdx.x;
    const int t = threadIdx.x;
    const int wv = t >> 6;
    const int lane = t & 63;
    __shared__ ull stage[NBANDS * CAPH];   // 32 KB: all hi keys fit
    __shared__ unsigned hist[4][256];      // wave-private histograms
    __shared__ unsigned sfx[256];
    __shared__ ull sel[256];
    __shared__ int s_ch[NBANDS], s_cl[NBANDS], s_oh[NBANDS + 1];
    __shared__ int s_ok;
    __shared__ int scnt;
    __shared__ unsigned s_pref;
    __shared__ int s_k, s_stop;
    __shared__ unsigned aW[4], oW[4], s_and, s_or, wsum[4];

    if (t == 0) { s_ok = 1; s_stop = 0; scnt = 0; }
    __syncthreads();
    if (t < NBANDS) {
        int raw = cnth[img * NBANDS + t];
        s_ch[t] = max(raw, 0);
        s_cl[t] = cntl[img * NBANDS + t];
        if (raw < 0) s_ok = 0;       // benign race: all writers store 0
    }
    __syncthreads();
    if (t == 0) {
        int a = 0;
        for (int b = 0; b < NBANDS; b++) { s_oh[b] = a; a += s_ch[b]; }
        s_oh[NBANDS] = a;
    }
    __syncthreads();
    const int nh = s_oh[NBANDS];
    const bool use_hi = (nh >= TOPK) && (s_ok != 0);

    if (use_hi) {
        int b = t >> 1, i0 = t & 1;              // 2 threads per band
        int nb = s_ch[b], ob = s_oh[b];
        const ull* p = cand_hi + (size_t)(img * NBANDS + b) * CAPH;
        for (int i = i0; i < nb; i += 2) stage[ob + i] = p[i];
    }
    __syncthreads();

    int n_tot = nh;
    if (!use_hi) {
        n_tot = 0;
        for (int b = 0; b < NBANDS; b++) n_tot += s_cl[b];
    }

    unsigned T = 0;   // value-bits threshold (partial or exact)
    if (n_tot > 256) {
        // ---- AND/OR over candidate value bits -> common high-byte prefix
        unsigned va = 0xFFFFFFFFu, vo = 0u;
        if (use_hi) {
            for (int i = t; i < nh; i += 256) {
                unsigned vb = (unsigned)(stage[i] >> 32);
                va &= vb; vo |= vb;
            }
        } else {
            for (int b = 0; b < NBANDS; b++) {
                int nb = s_cl[b];
                const ull* p = cand_lo + (size_t)(img * NBANDS + b) * capl;
                for (int i = t; i < nb; i += 256) {
                    unsigned vb = (unsigned)(p[i] >> 32);
                    va &= vb; vo |= vb;
                }
            }
        }
        #pragma unroll
        for (int off = 32; off > 0; off >>= 1) {
            va &= __shfl_xor(va, off);
            vo |= __shfl_xor(vo, off);
        }
        if (lane == 0) { aW[wv] = va; oW[wv] = vo; }
        __syncthreads();
        if (t == 0) {
            unsigned A = 0xFFFFFFFFu, O = 0u;
            for (int w = 0; w < 4; w++) { A &= aW[w]; O |= oW[w]; }
            s_and = A; s_or = O;
        }
        __syncthreads();
        const unsigned diff = s_and ^ s_or;
        int sb = 3;
        unsigned maskhi = 0u;
        while (sb >= 0 && ((diff >> (sb * 8)) & 0xFFu) == 0u) {
            maskhi |= 0xFFu << (sb * 8);
            sb--;
        }
        unsigned prefix = s_and & maskhi;

        if (sb < 0) {
            T = s_and;               // all candidate values identical
        } else {
            int kk = TOPK;
            for (int byte = sb; byte >= 0; byte--) {
                #pragma unroll
                for (int w = 0; w < 4; w++) hist[w][t] = 0;
                __syncthreads();
                const int shift = byte * 8;
                if (use_hi) {
                    for (int i = t; i < nh; i += 256) {
                        unsigned vb = (unsigned)(stage[i] >> 32);
                        if ((vb & maskhi) == prefix)
                            atomicAdd(&hist[wv][(vb >> shift) & 0xFFu], 1u);
                    }
                } else {
                    for (int b = 0; b < NBANDS; b++) {
                        int nb = s_cl[b];
                        const ull* p = cand_lo + (size_t)(img * NBANDS + b) * capl;
                        for (int i = t; i < nb; i += 256) {
                            unsigned vb = (unsigned)(p[i] >> 32);
                            if ((vb & maskhi) == prefix)
                                atomicAdd(&hist[wv][(vb >> shift) & 0xFFu], 1u);
                        }
                    }
                }
                __syncthreads();
                // suffix-scan of 256 bins: wave shuffle (2 barriers)
                unsigned v = hist[0][t] + hist[1][t] + hist[2][t] + hist[3][t];
                #pragma unroll
                for (int off = 1; off < 64; off <<= 1) {
                    unsigned u = __shfl_down(v, off);
                    if (lane + off < 64) v += u;
                }
                if (lane == 0) wsum[wv] = v;
                __syncthreads();
                unsigned add = 0;
                for (int w = wv + 1; w < 4; w++) add += wsum[w];
                unsigned myfx = v + add;         // count(matching, byte >= t)
                sfx[t] = myfx;
                __syncthreads();
                unsigned nxt = (t == 255) ? 0u : sfx[t + 1];
                if (myfx >= (unsigned)kk && nxt < (unsigned)kk) {
                    s_pref = prefix | ((unsigned)t << shift);
                    s_k = kk - (int)nxt;
                    // candidates {vb >= new partial T} = (TOPK-kk) + myfx
                    if ((TOPK - kk) + (int)myfx <= 256) s_stop = 1;
                }
                __syncthreads();
                prefix = s_pref;
                kk = s_k;
                maskhi |= (0xFFu << shift);
                if (s_stop) break;
            }
            T = prefix;
        }
    }

    __syncthreads();
    if (use_hi) {
        for (int i = t; i < nh; i += 256) {
            ull k = stage[i];
            if ((unsigned)(k >> 32) >= T) {
                int s = atomicAdd(&scnt, 1);
                if (s < 256) sel[s] = k;
            }
        }
    } else {
        for (int b = 0; b < NBANDS; b++) {
            int nb = s_cl[b];
            const ull* p = cand_lo + (size_t)(img * NBANDS + b) * capl;
            for (int i = t; i < nb; i += 256) {
                ull k = p[i];
                if ((unsigned)(k >> 32) >= T) {
                    int s = atomicAdd(&scnt, 1);
                    if (s < 256) sel[s] = k;
                }
            }
        }
    }
    __syncthreads();
    const int m = min(scnt, 256);
    ull* sorted = stage;               // stage is dead past this point
    if (t >= m) sel[t] = 0ull;
    sorted[t] = 0ull;
    __syncthreads();

    // ---- rank-select: exact descending order of unique full keys ----
    {
        ull k = sel[t];
        int rank = 0;
        for (int j = 0; j < 256; j++) rank += (sel[j] > k) ? 1 : 0;
        if (k != 0ull && rank < 256) sorted[rank] = k;
    }
    __syncthreads();

    // write: coords [NB,TOPK,2] then probs [NB,TOPK], all fp32
    if (t < TOPK) {
        ull key = sorted[t];
        float prob = 0.0f;
        unsigned row = 0, col = 0;
        if (key != 0ull) {
            prob = __uint_as_float((unsigned)(key >> 32));
            unsigned idx = 0xFFFFFFFFu - (unsigned)(key & 0xFFFFFFFFull);
            row = idx >> 10;
            col = idx & (W - 1);
        }
        size_t cbase = (size_t)img * TOPK * 2 + (size_t)t * 2;
        out[cbase + 0] = (float)row;
        out[cbase + 1] = (float)col;
        out[(size_t)NB * TOPK * 2 + (size_t)img * TOPK + t] = prob;
    }
}

extern "C" void kernel_launch(void* const* d_in, const int* in_sizes, int n_in,
                              void* d_out, int out_size, void* d_ws, size_t ws_size,
                              hipStream_t stream) {
    const float* center_map = (const float*)d_in[0];
    float* out = (float*)d_out;

    // workspace layout (counts plain-stored by peak_kernel; NO memset):
    //   [0, 16K)      : cntl[4096]
    //   [16K, 32K)    : cnth[4096]
    //   [32K, +1M)    : cand_hi[4096][CAPH]
    //   rest          : cand_lo[4096][capl]
    const int nbkt = NB * NBANDS;   // 4096
    int* cntl = (int*)d_ws;
    int* cnth = (int*)((char*)d_ws + 16384);
    ull* cand_hi = (ull*)((char*)d_ws + 32768);
    size_t hi_bytes = (size_t)nbkt * CAPH * sizeof(ull);   // 1 MB
    ull* cand_lo = (ull*)((char*)d_ws + 32768 + hi_bytes);
    size_t avail = (ws_size > 32768 + hi_bytes) ? (ws_size - 32768 - hi_bytes) : 0;
    int capl = (int)(avail / (nbkt * sizeof(ull)));
    if (capl > LBL) capl = LBL;
    if (capl < 1) capl = 1;

    dim3 gridA(NBANDS, NB);   // 128 x 32 = 4096 blocks
    peak_kernel<<<gridA, 256, 0, stream>>>(center_map, cand_hi, cand_lo,
                                           cntl, cnth, capl);

    topk_kernel<<<NB, 256, 0, stream>>>(cand_hi, cand_lo, cntl, cnth, out, capl);
}